// Round 1
// baseline (1244.916 us; speedup 1.0000x reference)
//
#include <hip/hip_runtime.h>

#define L 1024
#define CIN 512
#define NH 32
#define DH 64
#define NB 2
#define AF 2048

// ---------------------------------------------------------------------------
// Generic fp32 tiled GEMM: C[M,N] = A[M,K] * B[K,N] + bias[M], optional ReLU.
// 64x64 tile, BK=16, 256 threads, 4x4 micro-tile per thread.
// ---------------------------------------------------------------------------
template<int RELU>
__global__ __launch_bounds__(256) void gemm_bias(
    const float* __restrict__ A, const float* __restrict__ B,
    const float* __restrict__ bias, float* __restrict__ C,
    int M, int N, int K)
{
    __shared__ float As[16][64];   // As[k][m]
    __shared__ float Bs[16][64];   // Bs[k][n]
    const int t  = threadIdx.x;
    const int tx = t & 15, ty = t >> 4;
    const int row0 = blockIdx.y * 64;
    const int col0 = blockIdx.x * 64;
    const int am = t >> 2;            // 0..63 (tile row)
    const int ak = (t & 3) << 2;      // 0,4,8,12
    const int bk = t >> 4;            // 0..15
    const int bn = (t & 15) << 2;     // 0..60

    float acc[4][4] = {};

    for (int k0 = 0; k0 < K; k0 += 16) {
        float4 av = *(const float4*)(A + (size_t)(row0 + am) * K + k0 + ak);
        float4 bv = *(const float4*)(B + (size_t)(k0 + bk) * N + col0 + bn);
        __syncthreads();   // previous iteration's reads done before overwrite
        As[ak + 0][am] = av.x; As[ak + 1][am] = av.y;
        As[ak + 2][am] = av.z; As[ak + 3][am] = av.w;
        *(float4*)&Bs[bk][bn] = bv;
        __syncthreads();
        #pragma unroll
        for (int kk = 0; kk < 16; ++kk) {
            float4 a4 = *(float4*)&As[kk][ty << 2];
            float4 b4 = *(float4*)&Bs[kk][tx << 2];
            float ar[4] = {a4.x, a4.y, a4.z, a4.w};
            float br[4] = {b4.x, b4.y, b4.z, b4.w};
            #pragma unroll
            for (int i = 0; i < 4; ++i)
                #pragma unroll
                for (int j = 0; j < 4; ++j)
                    acc[i][j] = fmaf(ar[i], br[j], acc[i][j]);
        }
    }
    #pragma unroll
    for (int i = 0; i < 4; ++i) {
        int r = row0 + (ty << 2) + i;
        float bi = bias[r];
        float v0 = acc[i][0] + bi, v1 = acc[i][1] + bi;
        float v2 = acc[i][2] + bi, v3 = acc[i][3] + bi;
        if (RELU) {
            v0 = fmaxf(v0, 0.f); v1 = fmaxf(v1, 0.f);
            v2 = fmaxf(v2, 0.f); v3 = fmaxf(v3, 0.f);
        }
        float4 o = {v0, v1, v2, v3};
        *(float4*)(C + (size_t)r * N + col0 + (tx << 2)) = o;
    }
}

// ---------------------------------------------------------------------------
// Pass A: per-row softmax stats. Block = 64 rows (l) of one (b,h).
// s[l,m] = (sum_d q[d,l]k[d,m] - |l-m|) / 8.  Online (max, sum-exp) over m.
// grid.x = B*H*16  (bid>>4 = bh, bid&15 = l-tile)
// ---------------------------------------------------------------------------
__global__ __launch_bounds__(256) void attn_stats(
    const float* __restrict__ q, const float* __restrict__ k,
    float* __restrict__ rowmax, float* __restrict__ rowinv)
{
    __shared__ float qs[64][64];   // [d][l]
    __shared__ float ks[64][64];   // [d][m]
    const int t  = threadIdx.x;
    const int tx = t & 15, ty = t >> 4;
    const int lt = blockIdx.x & 15;
    const int bh = blockIdx.x >> 4;
    const float* qbh = q + (size_t)bh * DH * L;
    const float* kbh = k + (size_t)bh * DH * L;
    const int l0 = lt * 64;

    #pragma unroll
    for (int r = 0; r < 4; ++r) {
        int idx = r * 1024 + t * 4;
        int d = idx >> 6, l = idx & 63;
        *(float4*)&qs[d][l] = *(const float4*)(qbh + (size_t)d * L + l0 + l);
    }

    float M[4], S[4];
    #pragma unroll
    for (int i = 0; i < 4; ++i) { M[i] = -1e30f; S[i] = 0.f; }

    for (int mt = 0; mt < 16; ++mt) {
        __syncthreads();
        #pragma unroll
        for (int r = 0; r < 4; ++r) {
            int idx = r * 1024 + t * 4;
            int d = idx >> 6, m = idx & 63;
            *(float4*)&ks[d][m] = *(const float4*)(kbh + (size_t)d * L + mt * 64 + m);
        }
        __syncthreads();
        float att[4][4] = {};
        #pragma unroll
        for (int d = 0; d < 64; ++d) {
            float4 a4 = *(float4*)&qs[d][ty << 2];
            float4 b4 = *(float4*)&ks[d][tx << 2];
            float ar[4] = {a4.x, a4.y, a4.z, a4.w};
            float br[4] = {b4.x, b4.y, b4.z, b4.w};
            #pragma unroll
            for (int i = 0; i < 4; ++i)
                #pragma unroll
                for (int j = 0; j < 4; ++j)
                    att[i][j] = fmaf(ar[i], br[j], att[i][j]);
        }
        #pragma unroll
        for (int i = 0; i < 4; ++i) {
            int lg = l0 + (ty << 2) + i;
            float s[4];
            #pragma unroll
            for (int j = 0; j < 4; ++j) {
                int mg = mt * 64 + (tx << 2) + j;
                s[j] = (att[i][j] - fabsf((float)(lg - mg))) * 0.125f;
            }
            float tm = fmaxf(fmaxf(s[0], s[1]), fmaxf(s[2], s[3]));
            if (tm > M[i]) { S[i] *= __expf(M[i] - tm); M[i] = tm; }
            S[i] += __expf(s[0] - M[i]) + __expf(s[1] - M[i])
                  + __expf(s[2] - M[i]) + __expf(s[3] - M[i]);
        }
    }
    // reduce (M,S) across the 16 tx lanes owning the same row
    #pragma unroll
    for (int i = 0; i < 4; ++i) {
        float m_ = M[i], s_ = S[i];
        #pragma unroll
        for (int off = 1; off < 16; off <<= 1) {
            float m2 = __shfl_xor(m_, off);
            float s2 = __shfl_xor(s_, off);
            float mn = fmaxf(m_, m2);
            s_ = s_ * __expf(m_ - mn) + s2 * __expf(m2 - mn);
            m_ = mn;
        }
        if (tx == 0) {
            int lg = l0 + (ty << 2) + i;
            rowmax[(size_t)bh * L + lg] = m_;
            rowinv[(size_t)bh * L + lg] = 1.0f / s_;
        }
    }
}

// ---------------------------------------------------------------------------
// Pass B: O[d,m] = sum_{l<=m} v[d,l] * exp(s[l,m]-rowmax[l])*rowinv[l]
// Block = one (b,h, m-tile of 64). Iterates l-tiles 0..mt (triangular).
// h = relu(O) written to hbuf[b][h*64+d][m].
// ---------------------------------------------------------------------------
__global__ __launch_bounds__(256) void attn_pv(
    const float* __restrict__ q, const float* __restrict__ k,
    const float* __restrict__ v,
    const float* __restrict__ rowmax, const float* __restrict__ rowinv,
    float* __restrict__ hbuf)
{
    __shared__ float ks[64][64];    // [d][m]  (fixed for block)
    __shared__ float qs[64][64];    // [d][l]
    __shared__ float vsT[64][68];   // [l][d]  (padded: row stride 272B, 16B-aligned)
    __shared__ float ws[64][68];    // [l][m]
    const int t  = threadIdx.x;
    const int tx = t & 15, ty = t >> 4;
    const int mt = blockIdx.x & 15;
    const int bh = blockIdx.x >> 4;
    const float* qbh = q + (size_t)bh * DH * L;
    const float* kbh = k + (size_t)bh * DH * L;
    const float* vbh = v + (size_t)bh * DH * L;
    const int m0 = mt * 64;

    #pragma unroll
    for (int r = 0; r < 4; ++r) {
        int idx = r * 1024 + t * 4;
        int d = idx >> 6, m = idx & 63;
        *(float4*)&ks[d][m] = *(const float4*)(kbh + (size_t)d * L + m0 + m);
    }

    float acc[4][4] = {};

    for (int lt = 0; lt <= mt; ++lt) {
        const int l0 = lt * 64;
        __syncthreads();
        #pragma unroll
        for (int r = 0; r < 4; ++r) {
            int idx = r * 1024 + t * 4;
            int d = idx >> 6, l = idx & 63;
            *(float4*)&qs[d][l] = *(const float4*)(qbh + (size_t)d * L + l0 + l);
            float4 vv = *(const float4*)(vbh + (size_t)d * L + l0 + l);
            vsT[l + 0][d] = vv.x; vsT[l + 1][d] = vv.y;
            vsT[l + 2][d] = vv.z; vsT[l + 3][d] = vv.w;
        }
        __syncthreads();

        // phase 1: s tile (rows l = ty*4+i, cols m = tx*4+j) -> weights in ws
        float att[4][4] = {};
        #pragma unroll
        for (int d = 0; d < 64; ++d) {
            float4 a4 = *(float4*)&qs[d][ty << 2];
            float4 b4 = *(float4*)&ks[d][tx << 2];
            float ar[4] = {a4.x, a4.y, a4.z, a4.w};
            float br[4] = {b4.x, b4.y, b4.z, b4.w};
            #pragma unroll
            for (int i = 0; i < 4; ++i)
                #pragma unroll
                for (int j = 0; j < 4; ++j)
                    att[i][j] = fmaf(ar[i], br[j], att[i][j]);
        }
        #pragma unroll
        for (int i = 0; i < 4; ++i) {
            int ll = (ty << 2) + i;
            int lg = l0 + ll;
            float rm = rowmax[(size_t)bh * L + lg];
            float ri = rowinv[(size_t)bh * L + lg];
            float w[4];
            #pragma unroll
            for (int j = 0; j < 4; ++j) {
                int mg = m0 + (tx << 2) + j;
                float s = (att[i][j] - fabsf((float)(lg - mg))) * 0.125f;
                w[j] = (lg <= mg) ? __expf(s - rm) * ri : 0.f;
            }
            float4 wv = {w[0], w[1], w[2], w[3]};
            *(float4*)&ws[ll][tx << 2] = wv;
        }
        __syncthreads();

        // phase 2: acc[d=ty*4+i][m=tx*4+j] += sum_ll vsT[ll][d] * ws[ll][m]
        #pragma unroll
        for (int ll = 0; ll < 64; ++ll) {
            float4 a4 = *(float4*)&vsT[ll][ty << 2];
            float4 b4 = *(float4*)&ws[ll][tx << 2];
            float ar[4] = {a4.x, a4.y, a4.z, a4.w};
            float br[4] = {b4.x, b4.y, b4.z, b4.w};
            #pragma unroll
            for (int i = 0; i < 4; ++i)
                #pragma unroll
                for (int j = 0; j < 4; ++j)
                    acc[i][j] = fmaf(ar[i], br[j], acc[i][j]);
        }
    }

    #pragma unroll
    for (int i = 0; i < 4; ++i) {
        int d = (ty << 2) + i;
        float4 o;
        o.x = fmaxf(acc[i][0], 0.f);
        o.y = fmaxf(acc[i][1], 0.f);
        o.z = fmaxf(acc[i][2], 0.f);
        o.w = fmaxf(acc[i][3], 0.f);
        *(float4*)(hbuf + ((size_t)bh * DH + d) * L + m0 + (tx << 2)) = o;
    }
}

// ---------------------------------------------------------------------------
extern "C" void kernel_launch(void* const* d_in, const int* in_sizes, int n_in,
                              void* d_out, int out_size, void* d_ws, size_t ws_size,
                              hipStream_t stream)
{
    const float* x  = (const float*)d_in[0];
    const float* Wq = (const float*)d_in[1];
    const float* bq = (const float*)d_in[2];
    const float* Wk = (const float*)d_in[3];
    const float* bk = (const float*)d_in[4];
    const float* Wv = (const float*)d_in[5];
    const float* bv = (const float*)d_in[6];
    const float* W1 = (const float*)d_in[7];
    const float* b1 = (const float*)d_in[8];
    const float* W2 = (const float*)d_in[9];
    const float* b2 = (const float*)d_in[10];
    float* out = (float*)d_out;

    float* ws   = (float*)d_ws;
    float* qb   = ws;                    // [B][2048][1024] = 4M floats
    float* kb   = ws + 4194304;          // 4M
    float* vb   = ws + 8388608;          // 4M
    float* hbuf = ws + 12582912;         // 4M
    float* z1   = ws + 16777216;         // 4M
    float* rmax = ws + 20971520;         // 64K
    float* rinv = ws + 21037056;         // 64K

    dim3 blk(256);
    dim3 g1(L / 64, AF / 64);   // (16, 32)

    for (int b = 0; b < NB; ++b) {
        const float* xb = x + (size_t)b * CIN * L;
        gemm_bias<0><<<g1, blk, 0, stream>>>(Wq, xb, bq, qb + (size_t)b * AF * L, AF, L, CIN);
        gemm_bias<0><<<g1, blk, 0, stream>>>(Wk, xb, bk, kb + (size_t)b * AF * L, AF, L, CIN);
        gemm_bias<0><<<g1, blk, 0, stream>>>(Wv, xb, bv, vb + (size_t)b * AF * L, AF, L, CIN);
    }
    attn_stats<<<dim3(NB * NH * 16), blk, 0, stream>>>(qb, kb, rmax, rinv);
    attn_pv<<<dim3(NB * NH * 16), blk, 0, stream>>>(qb, kb, vb, rmax, rinv, hbuf);
    for (int b = 0; b < NB; ++b) {
        gemm_bias<1><<<g1, blk, 0, stream>>>(W1, hbuf + (size_t)b * AF * L, b1,
                                             z1 + (size_t)b * AF * L, AF, L, AF);
        gemm_bias<0><<<g1, blk, 0, stream>>>(W2, z1 + (size_t)b * AF * L, b2,
                                             out + (size_t)b * AF * L, AF, L, AF);
    }
}

// Round 2
// 223.888 us; speedup vs baseline: 5.5604x; 5.5604x over previous
//
#include <hip/hip_runtime.h>

#define L 1024
#define CIN 512
#define NH 32
#define DH 64
#define NB 2
#define AF 2048

typedef unsigned short u16;
typedef unsigned int u32;
typedef __attribute__((ext_vector_type(8))) short bfx8;   // 8 bf16 = 4 VGPR (MFMA A/B frag)
typedef __attribute__((ext_vector_type(4))) short bfx4;   // 8B half-frag
typedef __attribute__((ext_vector_type(4))) float fx4;    // MFMA C/D frag

struct __align__(8) us4 { u16 x, y, z, w; };

#define MFMA16 __builtin_amdgcn_mfma_f32_16x16x32_bf16

__device__ inline void gld16(const void* g, void* l) {
    __builtin_amdgcn_global_load_lds(
        (const __attribute__((address_space(1))) u32*)g,
        (__attribute__((address_space(3))) u32*)l, 16, 0, 0);
}

__device__ inline u16 f2b(float f) {
    union { float f; u32 u; } v; v.f = f;
    u32 u = v.u;
    return (u16)((u + 0x7fffu + ((u >> 16) & 1u)) >> 16);
}

// ---------------------------------------------------------------------------
// Elementwise fp32 -> bf16 convert (weights). n4 = element count / 4.
// ---------------------------------------------------------------------------
__global__ __launch_bounds__(256) void convert_f2b4(
    const float* __restrict__ in, u16* __restrict__ out, int n4)
{
    int i = blockIdx.x * 256 + threadIdx.x;
    int stride = gridDim.x * 256;
    for (; i < n4; i += stride) {
        float4 v = ((const float4*)in)[i];
        us4 o = { f2b(v.x), f2b(v.y), f2b(v.z), f2b(v.w) };
        ((us4*)out)[i] = o;
    }
}

// ---------------------------------------------------------------------------
// x [B][CIN][L] fp32 -> xT [B][L][CIN] bf16 (transpose + convert)
// grid (CIN/64, L/64, B), block 256
// ---------------------------------------------------------------------------
__global__ __launch_bounds__(256) void convert_xT(
    const float* __restrict__ x, u16* __restrict__ xT)
{
    const int c0 = blockIdx.x * 64, l0 = blockIdx.y * 64, b = blockIdx.z;
    __shared__ u16 tile[64][68];   // [c][l]
    const int t = threadIdx.x;
    const int tr = t >> 4, tc4 = (t & 15) * 4;
    #pragma unroll
    for (int p = 0; p < 4; ++p) {
        int c = p * 16 + tr;
        float4 v = *(const float4*)(x + ((size_t)(b * CIN + c0 + c)) * L + l0 + tc4);
        tile[c][tc4 + 0] = f2b(v.x); tile[c][tc4 + 1] = f2b(v.y);
        tile[c][tc4 + 2] = f2b(v.z); tile[c][tc4 + 3] = f2b(v.w);
    }
    __syncthreads();
    #pragma unroll
    for (int p = 0; p < 4; ++p) {
        int l = p * 16 + tr;
        us4 o = { tile[tc4 + 0][l], tile[tc4 + 1][l], tile[tc4 + 2][l], tile[tc4 + 3][l] };
        *(us4*)(xT + ((size_t)(b * L + l0 + l)) * CIN + c0 + tc4) = o;
    }
}

// ---------------------------------------------------------------------------
// bf16 transpose: in [B][L][AF] (vT[l][c]) -> out [B][AF][L] (v[c][l])
// grid (AF/64, L/64, B)
// ---------------------------------------------------------------------------
__global__ __launch_bounds__(256) void transpose_b(
    const u16* __restrict__ in, u16* __restrict__ out)
{
    const int c0 = blockIdx.x * 64, l0 = blockIdx.y * 64, b = blockIdx.z;
    __shared__ u16 tile[64][68];   // [l][c]
    const int t = threadIdx.x;
    const int tr = t >> 4, tc4 = (t & 15) * 4;
    #pragma unroll
    for (int p = 0; p < 4; ++p) {
        int l = p * 16 + tr;
        us4 v = *(const us4*)(in + ((size_t)(b * L + l0 + l)) * AF + c0 + tc4);
        tile[l][tc4 + 0] = v.x; tile[l][tc4 + 1] = v.y;
        tile[l][tc4 + 2] = v.z; tile[l][tc4 + 3] = v.w;
    }
    __syncthreads();
    #pragma unroll
    for (int p = 0; p < 4; ++p) {
        int c = p * 16 + tr;
        us4 o = { tile[tc4 + 0][c], tile[tc4 + 1][c], tile[tc4 + 2][c], tile[tc4 + 3][c] };
        *(us4*)(out + ((size_t)(b * AF + c0 + c)) * L + l0 + tc4) = o;
    }
}

// ---------------------------------------------------------------------------
// MFMA GEMM: C[M,N] = A[M,K] * B[K,N] (+bias[M], optional relu)
// A [M,K] bf16 row-major, BT [N,K] bf16 row-major (= B^T).
// CT_OUT=1: store C^T bf16 [N][M] (contiguous us4 stores).
// CT_OUT=0: store C fp32 [M][N].
// NA=3: grid.z = b*3+which, A/bias selected from {A0,A1,A2}; out += which*sWhich.
// 128x128 tile, BK=32, 256 threads (4 waves of 64x64).
// ---------------------------------------------------------------------------
template<int RELU, int CT_OUT, int NA>
__global__ __launch_bounds__(256) void gemm_bt(
    const u16* __restrict__ A0, const u16* __restrict__ A1, const u16* __restrict__ A2,
    const float* __restrict__ bias0, const float* __restrict__ bias1, const float* __restrict__ bias2,
    const u16* __restrict__ BTb, void* __restrict__ Cb,
    int M, int N, int K, size_t sBT, size_t sC, size_t sWhich)
{
    const int z = blockIdx.z;
    const int which = (NA == 3) ? (z % 3) : 0;
    const int b     = (NA == 3) ? (z / 3) : z;
    const u16* __restrict__ A = (which == 0) ? A0 : (which == 1) ? A1 : A2;
    const float* __restrict__ bias = (which == 0) ? bias0 : (which == 1) ? bias1 : bias2;
    const u16* __restrict__ BT = BTb + (size_t)b * sBT;
    const int m0 = blockIdx.y * 128, n0 = blockIdx.x * 128;

    __shared__ u16 lA[128 * 32];
    __shared__ u16 lB[128 * 32];

    const int t = threadIdx.x, lane = t & 63, wave = t >> 6;
    const int wm = (wave >> 1) * 64, wn = (wave & 1) * 64;
    const int rl = lane & 15, kh = lane >> 4;

    fx4 acc[4][4];
    #pragma unroll
    for (int i = 0; i < 4; ++i)
        #pragma unroll
        for (int j = 0; j < 4; ++j) acc[i][j] = (fx4){0.f, 0.f, 0.f, 0.f};

    // staging: 512 16B-slots; slot s -> row s>>2, chunk-pos s&3; src chunk = pos ^ ((r>>1)&3)
    const int s0 = t, s1 = t + 256;
    const int r0 = s0 >> 2, cs0 = (s0 & 3) ^ ((r0 >> 1) & 3);
    const int r1 = s1 >> 2, cs1 = (s1 & 3) ^ ((r1 >> 1) & 3);
    const u16* gA0 = A  + (size_t)(m0 + r0) * K + cs0 * 8;
    const u16* gA1 = A  + (size_t)(m0 + r1) * K + cs1 * 8;
    const u16* gB0 = BT + (size_t)(n0 + r0) * K + cs0 * 8;
    const u16* gB1 = BT + (size_t)(n0 + r1) * K + cs1 * 8;

    // frag read offsets (ushort idx): row r, k-chunk kh -> r*32 + ((kh ^ ((r>>1)&3))*8)
    int aoff[4], boff[4];
    #pragma unroll
    for (int f = 0; f < 4; ++f) {
        int ra = wm + f * 16 + rl;
        int rb = wn + f * 16 + rl;
        aoff[f] = ra * 32 + ((kh ^ ((ra >> 1) & 3)) * 8);
        boff[f] = rb * 32 + ((kh ^ ((rb >> 1) & 3)) * 8);
    }

    for (int k0 = 0; k0 < K; k0 += 32) {
        __syncthreads();
        gld16(gA0 + k0, lA + s0 * 8);
        gld16(gA1 + k0, lA + s1 * 8);
        gld16(gB0 + k0, lB + s0 * 8);
        gld16(gB1 + k0, lB + s1 * 8);
        __syncthreads();
        bfx8 af[4], bf[4];
        #pragma unroll
        for (int f = 0; f < 4; ++f) af[f] = *(const bfx8*)&lA[aoff[f]];
        #pragma unroll
        for (int f = 0; f < 4; ++f) bf[f] = *(const bfx8*)&lB[boff[f]];
        #pragma unroll
        for (int fm = 0; fm < 4; ++fm)
            #pragma unroll
            for (int fn = 0; fn < 4; ++fn)
                acc[fm][fn] = MFMA16(af[fm], bf[fn], acc[fm][fn], 0, 0, 0);
    }

    if (CT_OUT) {
        u16* CT = (u16*)Cb + (size_t)which * sWhich + (size_t)b * sC;
        #pragma unroll
        for (int fm = 0; fm < 4; ++fm) {
            int mg = m0 + wm + fm * 16 + kh * 4;
            float bi0 = bias[mg], bi1 = bias[mg + 1], bi2 = bias[mg + 2], bi3 = bias[mg + 3];
            #pragma unroll
            for (int fn = 0; fn < 4; ++fn) {
                int ng = n0 + wn + fn * 16 + rl;
                float v0 = acc[fm][fn][0] + bi0;
                float v1 = acc[fm][fn][1] + bi1;
                float v2 = acc[fm][fn][2] + bi2;
                float v3 = acc[fm][fn][3] + bi3;
                if (RELU) {
                    v0 = fmaxf(v0, 0.f); v1 = fmaxf(v1, 0.f);
                    v2 = fmaxf(v2, 0.f); v3 = fmaxf(v3, 0.f);
                }
                us4 o = { f2b(v0), f2b(v1), f2b(v2), f2b(v3) };
                *(us4*)(CT + (size_t)ng * M + mg) = o;
            }
        }
    } else {
        float* C = (float*)Cb + (size_t)b * sC;
        #pragma unroll
        for (int fm = 0; fm < 4; ++fm) {
            int mg = m0 + wm + fm * 16 + kh * 4;
            #pragma unroll
            for (int fn = 0; fn < 4; ++fn) {
                int ng = n0 + wn + fn * 16 + rl;
                #pragma unroll
                for (int r = 0; r < 4; ++r) {
                    float v = acc[fm][fn][r] + bias[mg + r];
                    if (RELU) v = fmaxf(v, 0.f);
                    C[(size_t)(mg + r) * N + ng] = v;
                }
            }
        }
    }
}

// ---------------------------------------------------------------------------
// Pass A: softmax stats. Block = 64 l-rows of one (b,h). grid (L/64, B*H).
// att^T tile = mfma(A=kT rows m, BT=qT rows l); per-lane online (max,sum) over m.
// ---------------------------------------------------------------------------
__global__ __launch_bounds__(256) void attn_stats(
    const u16* __restrict__ qT, const u16* __restrict__ kT,
    float* __restrict__ rmax, float* __restrict__ rinv)
{
    const int lt = blockIdx.x;
    const int bh = blockIdx.y;
    const int b = bh >> 5, h = bh & 31;
    const size_t base = (size_t)b * L * AF + h * DH;

    __shared__ u16 lq[64 * 64];
    __shared__ u16 lk[64 * 64];
    __shared__ float sM[4][64], sS[4][64];

    const int t = threadIdx.x, lane = t & 63, wave = t >> 6;
    const int rl = lane & 15, g = lane >> 4;

    // staging: 512 slots of 16B; slot -> row s>>3, chunk-pos s&7; src = pos ^ (r&7)
    const int s0 = t, s1 = t + 256;
    const int r0 = s0 >> 3, cs0 = (s0 & 7) ^ (r0 & 7);
    const int r1 = s1 >> 3, cs1 = (s1 & 7) ^ (r1 & 7);

    gld16(qT + base + (size_t)(lt * 64 + r0) * AF + cs0 * 8, lq + s0 * 8);
    gld16(qT + base + (size_t)(lt * 64 + r1) * AF + cs1 * 8, lq + s1 * 8);

    float Mx[4], Sx[4];
    #pragma unroll
    for (int f = 0; f < 4; ++f) { Mx[f] = -1e30f; Sx[f] = 0.f; }

    const int rmr = wave * 16 + rl;
    const int akoff0 = rmr * 64 + ((g ^ (rmr & 7)) * 8);
    const int akoff1 = rmr * 64 + (((g + 4) ^ (rmr & 7)) * 8);
    int qoff0[4], qoff1[4];
    #pragma unroll
    for (int f = 0; f < 4; ++f) {
        int rq = f * 16 + rl;
        qoff0[f] = rq * 64 + ((g ^ (rq & 7)) * 8);
        qoff1[f] = rq * 64 + (((g + 4) ^ (rq & 7)) * 8);
    }

    const u16* gk0 = kT + base + (size_t)r0 * AF + cs0 * 8;
    const u16* gk1 = kT + base + (size_t)r1 * AF + cs1 * 8;

    for (int mt = 0; mt < 16; ++mt) {
        __syncthreads();
        gld16(gk0 + (size_t)mt * 64 * AF, lk + s0 * 8);
        gld16(gk1 + (size_t)mt * 64 * AF, lk + s1 * 8);
        __syncthreads();
        bfx8 ak0 = *(const bfx8*)&lk[akoff0];
        bfx8 ak1 = *(const bfx8*)&lk[akoff1];
        #pragma unroll
        for (int fn = 0; fn < 4; ++fn) {
            bfx8 q0 = *(const bfx8*)&lq[qoff0[fn]];
            bfx8 q1 = *(const bfx8*)&lq[qoff1[fn]];
            fx4 att = (fx4){0.f, 0.f, 0.f, 0.f};
            att = MFMA16(ak0, q0, att, 0, 0, 0);
            att = MFMA16(ak1, q1, att, 0, 0, 0);
            const int lg = lt * 64 + fn * 16 + rl;
            const int mb = mt * 64 + wave * 16 + g * 4;
            float sv0 = (att[0] - fabsf((float)(lg - (mb + 0)))) * 0.125f;
            float sv1 = (att[1] - fabsf((float)(lg - (mb + 1)))) * 0.125f;
            float sv2 = (att[2] - fabsf((float)(lg - (mb + 2)))) * 0.125f;
            float sv3 = (att[3] - fabsf((float)(lg - (mb + 3)))) * 0.125f;
            float tm = fmaxf(fmaxf(sv0, sv1), fmaxf(sv2, sv3));
            if (tm > Mx[fn]) { Sx[fn] *= __expf(Mx[fn] - tm); Mx[fn] = tm; }
            Sx[fn] += __expf(sv0 - Mx[fn]) + __expf(sv1 - Mx[fn])
                    + __expf(sv2 - Mx[fn]) + __expf(sv3 - Mx[fn]);
        }
    }
    #pragma unroll
    for (int fn = 0; fn < 4; ++fn) {
        float m_ = Mx[fn], s_ = Sx[fn];
        #pragma unroll
        for (int off = 16; off <= 32; off <<= 1) {
            float m2 = __shfl_xor(m_, off);
            float s2 = __shfl_xor(s_, off);
            float mn = fmaxf(m_, m2);
            s_ = s_ * __expf(m_ - mn) + s2 * __expf(m2 - mn);
            m_ = mn;
        }
        if (lane < 16) { sM[wave][fn * 16 + rl] = m_; sS[wave][fn * 16 + rl] = s_; }
    }
    __syncthreads();
    if (t < 64) {
        float m_ = sM[0][t], s_ = sS[0][t];
        #pragma unroll
        for (int w = 1; w < 4; ++w) {
            float m2 = sM[w][t], s2 = sS[w][t];
            float mn = fmaxf(m_, m2);
            s_ = s_ * __expf(m_ - mn) + s2 * __expf(m2 - mn);
            m_ = mn;
        }
        rmax[(size_t)bh * L + lt * 64 + t] = m_;
        rinv[(size_t)bh * L + lt * 64 + t] = 1.0f / s_;
    }
}

// ---------------------------------------------------------------------------
// Pass B: O[d,m] = sum_{l<=m} v[d,l]*w[l,m]; h = relu(O) -> hT[b][m][h*64+d].
// Block = (b,h) x m-tile-pair (mt, 15-mt): 17 l-tile units each (balanced).
// grid (8, B*H).
// ---------------------------------------------------------------------------
__global__ __launch_bounds__(256) void attn_pv(
    const u16* __restrict__ qT, const u16* __restrict__ kT, const u16* __restrict__ v,
    const float* __restrict__ rmax, const float* __restrict__ rinv,
    u16* __restrict__ hT)
{
    const int pair = blockIdx.x;
    const int bh = blockIdx.y;
    const int b = bh >> 5, h = bh & 31;
    const size_t qkbase = (size_t)b * L * AF + h * DH;
    const size_t vbase  = ((size_t)b * AF + h * DH) * L;
    const size_t rbase  = (size_t)bh * L;

    __shared__ u16 lkt[64 * 64], lqt[64 * 64], lv[64 * 64];
    __shared__ u16 lw[64 * 68];   // wT[m][l], pad 68 (writes conflict-free)

    const int t = threadIdx.x, lane = t & 63, wave = t >> 6;
    const int rl = lane & 15, g = lane >> 4;

    const int s0 = t, s1 = t + 256;
    const int r0 = s0 >> 3, cs0 = (s0 & 7) ^ (r0 & 7);
    const int r1 = s1 >> 3, cs1 = (s1 & 7) ^ (r1 & 7);

    const u16* gq0 = qT + qkbase + (size_t)r0 * AF + cs0 * 8;
    const u16* gq1 = qT + qkbase + (size_t)r1 * AF + cs1 * 8;
    const u16* gv0 = v + vbase + (size_t)r0 * L + cs0 * 8;
    const u16* gv1 = v + vbase + (size_t)r1 * L + cs1 * 8;

    const int rmr = wave * 16 + rl;     // phase-1 A rows (m), phase-2 A rows (d)
    const int toff0 = rmr * 64 + ((g ^ (rmr & 7)) * 8);
    const int toff1 = rmr * 64 + (((g + 4) ^ (rmr & 7)) * 8);
    int qoff0[4], qoff1[4];
    #pragma unroll
    for (int f = 0; f < 4; ++f) {
        int rq = f * 16 + rl;
        qoff0[f] = rq * 64 + ((g ^ (rq & 7)) * 8);
        qoff1[f] = rq * 64 + (((g + 4) ^ (rq & 7)) * 8);
    }

    for (int half = 0; half < 2; ++half) {
        const int mt = half ? pair : 15 - pair;
        const int m0 = mt * 64;
        __syncthreads();   // previous half's phase-2 done with lv/lw; lkt free
        gld16(kT + qkbase + (size_t)(m0 + r0) * AF + cs0 * 8, lkt + s0 * 8);
        gld16(kT + qkbase + (size_t)(m0 + r1) * AF + cs1 * 8, lkt + s1 * 8);

        fx4 oa[4];
        #pragma unroll
        for (int f = 0; f < 4; ++f) oa[f] = (fx4){0.f, 0.f, 0.f, 0.f};

        for (int lt = 0; lt <= mt; ++lt) {
            __syncthreads();   // prev phase-2 done reading lv/lw; drains lkt gld (iter 0)
            gld16(gq0 + (size_t)lt * 64 * AF, lqt + s0 * 8);
            gld16(gq1 + (size_t)lt * 64 * AF, lqt + s1 * 8);
            gld16(gv0 + lt * 64, lv + s0 * 8);
            gld16(gv1 + lt * 64, lv + s1 * 8);
            __syncthreads();   // all stages complete

            // phase 1: att^T[m][l] = mfma(kT rows m, qT rows l); -> weights in lw
            bfx8 ak0 = *(const bfx8*)&lkt[toff0];
            bfx8 ak1 = *(const bfx8*)&lkt[toff1];
            #pragma unroll
            for (int fn = 0; fn < 4; ++fn) {
                bfx8 q0 = *(const bfx8*)&lqt[qoff0[fn]];
                bfx8 q1 = *(const bfx8*)&lqt[qoff1[fn]];
                fx4 att = (fx4){0.f, 0.f, 0.f, 0.f};
                att = MFMA16(ak0, q0, att, 0, 0, 0);
                att = MFMA16(ak1, q1, att, 0, 0, 0);
                const int lg = lt * 64 + fn * 16 + rl;
                float rm = rmax[rbase + lg];
                float ri = rinv[rbase + lg];
                #pragma unroll
                for (int r = 0; r < 4; ++r) {
                    int mloc = wave * 16 + g * 4 + r;
                    int mg = m0 + mloc;
                    float s = (att[r] - fabsf((float)(lg - mg))) * 0.125f;
                    float w = (lg <= mg) ? __expf(s - rm) * ri : 0.f;
                    lw[mloc * 68 + fn * 16 + rl] = f2b(w);
                }
            }
            __syncthreads();   // lw complete

            // phase 2: O[d][m] += mfma(v rows d, wT rows m)
            bfx8 av0 = *(const bfx8*)&lv[toff0];
            bfx8 av1 = *(const bfx8*)&lv[toff1];
            #pragma unroll
            for (int fn = 0; fn < 4; ++fn) {
                const u16* wrow = &lw[(fn * 16 + rl) * 68];
                union { bfx8 f; bfx4 h[2]; } w0, w1;   // 8B-aligned b64 pair loads
                w0.h[0] = *(const bfx4*)&wrow[g * 8];
                w0.h[1] = *(const bfx4*)&wrow[g * 8 + 4];
                w1.h[0] = *(const bfx4*)&wrow[(g + 4) * 8];
                w1.h[1] = *(const bfx4*)&wrow[(g + 4) * 8 + 4];
                oa[fn] = MFMA16(av0, w0.f, oa[fn], 0, 0, 0);
                oa[fn] = MFMA16(av1, w1.f, oa[fn], 0, 0, 0);
            }
        }

        // epilogue: relu, C^T store -> hT[b][m][h*64+d]
        #pragma unroll
        for (int fn = 0; fn < 4; ++fn) {
            int mg = m0 + fn * 16 + rl;
            int cg = h * DH + wave * 16 + g * 4;
            us4 o = { f2b(fmaxf(oa[fn][0], 0.f)), f2b(fmaxf(oa[fn][1], 0.f)),
                      f2b(fmaxf(oa[fn][2], 0.f)), f2b(fmaxf(oa[fn][3], 0.f)) };
            *(us4*)(hT + ((size_t)b * L + mg) * AF + cg) = o;
        }
    }
}

// ---------------------------------------------------------------------------
extern "C" void kernel_launch(void* const* d_in, const int* in_sizes, int n_in,
                              void* d_out, int out_size, void* d_ws, size_t ws_size,
                              hipStream_t stream)
{
    (void)in_sizes; (void)n_in; (void)out_size; (void)ws_size;
    const float* x  = (const float*)d_in[0];
    const float* Wq = (const float*)d_in[1];
    const float* bq = (const float*)d_in[2];
    const float* Wk = (const float*)d_in[3];
    const float* bk = (const float*)d_in[4];
    const float* Wv = (const float*)d_in[5];
    const float* bv = (const float*)d_in[6];
    const float* W1 = (const float*)d_in[7];
    const float* b1 = (const float*)d_in[8];
    const float* W2 = (const float*)d_in[9];
    const float* b2 = (const float*)d_in[10];

    u16* wsp = (u16*)d_ws;
    size_t o = 0;
    u16* xT  = wsp + o; o += (size_t)NB * L * CIN;     // 1,048,576
    u16* qT  = wsp + o; o += (size_t)NB * L * AF;      // 4,194,304
    u16* kT  = wsp + o; o += (size_t)NB * L * AF;
    u16* vT  = wsp + o; o += (size_t)NB * L * AF;
    u16* vdm = wsp + o; o += (size_t)NB * AF * L;
    u16* hT  = wsp + o; o += (size_t)NB * L * AF;
    u16* z1T = wsp + o; o += (size_t)NB * L * AF;
    u16* Wqb = wsp + o; o += (size_t)AF * CIN;
    u16* Wkb = wsp + o; o += (size_t)AF * CIN;
    u16* Wvb = wsp + o; o += (size_t)AF * CIN;
    u16* W1b = wsp + o; o += (size_t)AF * AF;
    u16* W2b = wsp + o; o += (size_t)AF * AF;
    float* rmax = (float*)(wsp + o); o += (size_t)NB * NH * L * 2;
    float* rinv = (float*)(wsp + o); o += (size_t)NB * NH * L * 2;

    dim3 blk(256);

    convert_xT<<<dim3(CIN / 64, L / 64, NB), blk, 0, stream>>>(x, xT);
    convert_f2b4<<<dim3(1024), blk, 0, stream>>>(Wq, Wqb, AF * CIN / 4);
    convert_f2b4<<<dim3(1024), blk, 0, stream>>>(Wk, Wkb, AF * CIN / 4);
    convert_f2b4<<<dim3(1024), blk, 0, stream>>>(Wv, Wvb, AF * CIN / 4);
    convert_f2b4<<<dim3(2048), blk, 0, stream>>>(W1, W1b, AF * AF / 4);
    convert_f2b4<<<dim3(2048), blk, 0, stream>>>(W2, W2b, AF * AF / 4);

    // QKV: qT/kT/vT = (W? * x)^T, fused over {q,k,v} x {b}: grid.z = b*3+which
    gemm_bt<0, 1, 3><<<dim3(L / 128, AF / 128, NB * 3), blk, 0, stream>>>(
        Wqb, Wkb, Wvb, bq, bk, bv, xT, qT,
        AF, L, CIN, (size_t)L * CIN, (size_t)L * AF, (size_t)NB * L * AF);

    transpose_b<<<dim3(AF / 64, L / 64, NB), blk, 0, stream>>>(vT, vdm);
    attn_stats<<<dim3(L / 64, NB * NH), blk, 0, stream>>>(qT, kT, rmax, rinv);
    attn_pv<<<dim3(8, NB * NH), blk, 0, stream>>>(qT, kT, vdm, rmax, rinv, hT);

    // z1T = relu(W1*h + b1)^T
    gemm_bt<1, 1, 1><<<dim3(L / 128, AF / 128, NB), blk, 0, stream>>>(
        W1b, nullptr, nullptr, b1, nullptr, nullptr, hT, z1T,
        AF, L, AF, (size_t)L * AF, (size_t)L * AF, 0);
    // out = W2*z1 + b2 (fp32, normal orientation)
    gemm_bt<0, 0, 1><<<dim3(L / 128, AF / 128, NB), blk, 0, stream>>>(
        W2b, nullptr, nullptr, b2, nullptr, nullptr, z1T, d_out,
        AF, L, AF, (size_t)L * AF, (size_t)AF * L, 0);
}